// Round 6
// baseline (219.500 us; speedup 1.0000x reference)
//
#include <hip/hip_runtime.h>
#include <cstdint>
#include <cstddef>

// InterpAttentionKHeadsNet — round 6: 32x32x16 MFMA layers + conflict-free-by-
// construction LDS (ROWB = 560 = 35*16: odd multiple of 16 so byte/16 mod 8 =
// 3*row + k-chunk spreads every lane group across all bank pairs; <=2-way
// aliasing everywhere, zero swizzle VALU), single ds_read_b128 B-frags
// (no lo/hi shufflevector movs), rel handled as one 16-wide tail k-step.
// Q/softmax/S keep the verified r5 16x16 wave-local path on new addressing.
// launch_bounds(256,4): acc 64 VGPR + ~16 frags ~= 100 < 128 cap; WRITE_SIZE
// is the spill tripwire.

#define NLAT 256
#define KNB 16
#define QB 4
#define MROWS 64       // QB*KNB rows per block
#define ROWB 560       // 280 f16: 256 ch + rel(3)+zeros(13) + 8 f16 pad

typedef float    f32x4  __attribute__((ext_vector_type(4)));
typedef float    f32x16 __attribute__((ext_vector_type(16)));
typedef _Float16 f16x8  __attribute__((ext_vector_type(8)));
typedef _Float16 f16x4  __attribute__((ext_vector_type(4)));

struct Smem {
  unsigned char buf[MROWS * ROWB];  // 35840 B, in-place activations
  float Sp[4][MROWS];
  float Sv[MROWS];
  int sidx[MROWS];
  int is64;
};

// In-place layer: C'[ch 64-slice][m 64] = W x H^T via 2x2 tiles of 32x32x16.
// Wp pack: f16 elem dst = ks*4096 + ch*16 + h*8 + e  (k = ks*16 + h*8 + e).
__device__ __forceinline__ void layer_mfma32(
    unsigned char* __restrict__ buf, const unsigned short* __restrict__ Wp,
    const float* __restrict__ bias, const float* __restrict__ W1f,
    int lane, int wave, bool relu)
{
  const int lm32 = lane & 31, h = lane >> 5;
  // B-frag: row = mt*32+lm32, k = ks*16 + h*8 -> byte = row*560 + ks*32 + h*16
  const char* bp = (const char*)buf + lm32 * 560 + h * 16;
  // A-frag: ch = (wave*2+ct)*32 + lm32 -> byte = ks*8192 + ch*32 + h*16
  const char* wbase = (const char*)Wp + (wave * 2) * 1024 + lm32 * 32 + h * 16;

  f32x16 acc[2][2];
#pragma unroll
  for (int i = 0; i < 2; ++i)
#pragma unroll
    for (int j = 0; j < 2; ++j) acc[i][j] = (f32x16)(0.f);

#pragma unroll
  for (int ks = 0; ks < 16; ++ks) {
    f16x8 a[2], b[2];
#pragma unroll
    for (int ct = 0; ct < 2; ++ct)
      a[ct] = *(const f16x8*)(wbase + ks * 8192 + ct * 1024);
#pragma unroll
    for (int mt = 0; mt < 2; ++mt)
      b[mt] = *(const f16x8*)(bp + mt * 17920 + ks * 32);
#pragma unroll
    for (int ct = 0; ct < 2; ++ct)
#pragma unroll
      for (int mt = 0; mt < 2; ++mt)
        acc[ct][mt] = __builtin_amdgcn_mfma_f32_32x32x16_f16(a[ct], b[mt], acc[ct][mt], 0, 0, 0);
  }
  if (W1f) {  // tail k-step: k = 256..271 (rel 256-258, zeros to 271)
    f16x8 a[2], b[2];
#pragma unroll
    for (int ct = 0; ct < 2; ++ct) {
      f16x8 v = {0, 0, 0, 0, 0, 0, 0, 0};
      if (h == 0) {
        const int ch = (wave * 2 + ct) * 32 + lm32;
        const float* wt = W1f + (size_t)ch * 259 + 256;
        v[0] = (_Float16)wt[0]; v[1] = (_Float16)wt[1]; v[2] = (_Float16)wt[2];
      }
      a[ct] = v;
    }
#pragma unroll
    for (int mt = 0; mt < 2; ++mt)
      b[mt] = *(const f16x8*)(bp + mt * 17920 + 512);
#pragma unroll
    for (int ct = 0; ct < 2; ++ct)
#pragma unroll
      for (int mt = 0; mt < 2; ++mt)
        acc[ct][mt] = __builtin_amdgcn_mfma_f32_32x32x16_f16(a[ct], b[mt], acc[ct][mt], 0, 0, 0);
  }
  __syncthreads();  // all reads done -> safe to overwrite in place
  // C layout (32x32): col m = lane&31, ch-row = (r&3) + 8*(r>>2) + 4h.
#pragma unroll
  for (int ct = 0; ct < 2; ++ct) {
#pragma unroll
    for (int q = 0; q < 4; ++q) {
      const int ch0 = (wave * 2 + ct) * 32 + q * 8 + h * 4;
      const float4 bs = *(const float4*)(bias + ch0);
      const float bb[4] = {bs.x, bs.y, bs.z, bs.w};
#pragma unroll
      for (int mt = 0; mt < 2; ++mt) {
        f16x4 v;
#pragma unroll
        for (int j = 0; j < 4; ++j) {
          float x = acc[ct][mt][q * 4 + j] + bb[j];
          if (relu) x = fmaxf(x, 0.f);
          v[j] = (_Float16)x;
        }
        *(f16x4*)((char*)buf + (mt * 32 + lm32) * 560 + ch0 * 2) = v;
      }
    }
  }
}

extern "C" __global__ __launch_bounds__(256, 4)
void interp_mfma(const float* __restrict__ latents,
                 const float* __restrict__ pts,
                 const float* __restrict__ ptsq,
                 const void*  __restrict__ proj,
                 const unsigned short* __restrict__ Lt_u,   // fp16 [B][N][256]
                 const float* __restrict__ W1f,             // fp32 [256][259]
                 const unsigned short* __restrict__ W1p,
                 const unsigned short* __restrict__ W2p,
                 const unsigned short* __restrict__ W3p,
                 const unsigned short* __restrict__ Wqh,    // fp16 [64][256] row-major
                 const float* __restrict__ b1, const float* __restrict__ b2,
                 const float* __restrict__ b3, const float* __restrict__ bq,
                 const float* __restrict__ wv8, const float* __restrict__ c0p,
                 float* __restrict__ out,
                 int N, int NQ, int use_lt)
{
  __shared__ Smem sm;
  const int tid = threadIdx.x;
  const int bid = blockIdx.x;
  const int lane = tid & 63, wave = tid >> 6;
  const int lm = lane & 15, lk = lane >> 4;

  if (tid == 0) {
    const int* p = (const int*)proj;
    int z = 1;
    for (int i = 0; i < 64; ++i) z &= (p[2 * i + 1] == 0);
    sm.is64 = z;
  }
  __syncthreads();
  if (tid < MROWS) {
    long long g = (long long)bid * QB + (tid >> 4);
    long long base = g * KNB + (tid & 15);
    sm.sidx[tid] = sm.is64 ? (int)((const long long*)proj)[base]
                           : ((const int*)proj)[base];
  }
  __syncthreads();

  // ---- gather: thread (row = tid&63, part = tid>>6) fills ch part*64..+63
  {
    const int row = tid & 63, part = tid >> 6;
    const int id = sm.sidx[row];
    const long long g = (long long)bid * QB + (row >> 4);
    const int b = (int)(g / NQ);
    char* dst = (char*)sm.buf + row * 560 + part * 128;
    if (use_lt) {
      const _Float16* src = (const _Float16*)Lt_u + ((size_t)b * N + id) * NLAT + part * 64;
#pragma unroll
      for (int cc = 0; cc < 8; ++cc)
        *(f16x8*)(dst + cc * 16) = *(const f16x8*)(src + cc * 8);
    } else {
      for (int cc = 0; cc < 8; ++cc) {
        f16x8 v;
#pragma unroll
        for (int e = 0; e < 8; ++e)
          v[e] = (_Float16)latents[((size_t)b * NLAT + part * 64 + cc * 8 + e) * N + id];
        *(f16x8*)(dst + cc * 16) = v;
      }
    }
    if (part == 0) {  // tail k 256..271: rel + zeros (pad bytes 544.. unread)
      const int nq = (int)(g - (long long)b * NQ);
      f16x8 v = {0, 0, 0, 0, 0, 0, 0, 0};
#pragma unroll
      for (int j = 0; j < 3; ++j)
        v[j] = (_Float16)(ptsq[((size_t)b * 3 + j) * NQ + nq]
                        - pts[((size_t)b * 3 + j) * N + id]);
      const f16x8 z = {0, 0, 0, 0, 0, 0, 0, 0};
      *(f16x8*)((char*)sm.buf + row * 560 + 512) = v;
      *(f16x8*)((char*)sm.buf + row * 560 + 528) = z;
    }
  }
  __syncthreads();

  layer_mfma32(sm.buf, W1p, b1, W1f, lane, wave, true);
  __syncthreads();
  layer_mfma32(sm.buf, W2p, b2, nullptr, lane, wave, true);
  __syncthreads();
  layer_mfma32(sm.buf, W3p, b3, nullptr, lane, wave, true);
  __syncthreads();

  // ---- Q heads (16x16 path; wave owns 16 heads), acc in regs
  // B-frag: row = mt*16+lm, k = ks*32 + lk*8 -> byte = row*560 + ks*64 + lk*16
  const char* bp16 = (const char*)sm.buf + lm * 560 + lk * 16;
  f32x4 qacc[4];
#pragma unroll
  for (int mt = 0; mt < 4; ++mt) qacc[mt] = (f32x4){0.f, 0.f, 0.f, 0.f};
  {
    const char* wqb = (const char*)Wqh + (wave * 16 + lm) * 512 + lk * 16;
#pragma unroll
    for (int ks = 0; ks < 8; ++ks) {
      f16x8 a = *(const f16x8*)(wqb + ks * 64);
#pragma unroll
      for (int mt = 0; mt < 4; ++mt) {
        f16x8 bf = *(const f16x8*)(bp16 + mt * 8960 + ks * 64);
        qacc[mt] = __builtin_amdgcn_mfma_f32_16x16x32_f16(a, bf, qacc[mt], 0, 0, 0);
      }
    }
  }
  // ---- S[m] = wv8 . H3[m] for row = wave*16+lm, k-chunks (cc*4+lk)*8
  {
    const char* sp = (const char*)sm.buf + (wave * 16 + lm) * 560 + lk * 16;
    float sacc = 0.f;
#pragma unroll
    for (int cc = 0; cc < 8; ++cc) {
      f16x8 v = *(const f16x8*)(sp + cc * 64);
      const int k0 = cc * 32 + lk * 8;
      const float4 w0 = *(const float4*)(wv8 + k0);
      const float4 w1 = *(const float4*)(wv8 + k0 + 4);
      sacc += (float)v[0] * w0.x + (float)v[1] * w0.y
            + (float)v[2] * w0.z + (float)v[3] * w0.w;
      sacc += (float)v[4] * w1.x + (float)v[5] * w1.y
            + (float)v[6] * w1.z + (float)v[7] * w1.w;
    }
    sacc += __shfl_xor(sacc, 16);
    sacc += __shfl_xor(sacc, 32);
    if (lk == 0) sm.Sv[wave * 16 + lm] = sacc;
  }

  // ---- in-register softmax over nb (= lm lanes) per head; mean over heads
  {
    float bqv[4];
#pragma unroll
    for (int r = 0; r < 4; ++r) bqv[r] = bq[wave * 16 + lk * 4 + r];
#pragma unroll
    for (int mt = 0; mt < 4; ++mt) {
      float sw = 0.f;
#pragma unroll
      for (int r = 0; r < 4; ++r) {
        const float qv = qacc[mt][r] + bqv[r];
        float mx = qv;
#pragma unroll
        for (int msk = 1; msk < 16; msk <<= 1) mx = fmaxf(mx, __shfl_xor(mx, msk));
        const float e = __expf(qv - mx);
        float s = e;
#pragma unroll
        for (int msk = 1; msk < 16; msk <<= 1) s += __shfl_xor(s, msk);
        sw += e / s;
      }
      sw += __shfl_xor(sw, 16);
      sw += __shfl_xor(sw, 32);
      if (lk == 0) sm.Sp[wave][mt * 16 + lm] = sw;
    }
  }
  __syncthreads();

  // ---- out[q] = sum_nb att[m]*S[m] + c0; wave w handles q = w
  {
    const int m = wave * 16 + lm;
    const float a = (sm.Sp[0][m] + sm.Sp[1][m] + sm.Sp[2][m] + sm.Sp[3][m]) * (1.f / 64.f);
    float val = a * sm.Sv[m];
#pragma unroll
    for (int msk = 1; msk < 16; msk <<= 1) val += __shfl_xor(val, msk);
    if (lane == 0) out[(long long)bid * QB + wave] = val + c0p[0];
  }
}

// ---- prep: fp32 -> fp16 packs; wv8 = W8*Wv fold; c0 = b8 + W8.bv ----
extern "C" __global__ void prep_w(const float* __restrict__ W1, const float* __restrict__ W2,
                                  const float* __restrict__ W3, const float* __restrict__ Wq,
                                  const float* __restrict__ Wv, const float* __restrict__ W8,
                                  const float* __restrict__ bv, const float* __restrict__ b8,
                                  unsigned short* W1p, unsigned short* W2p,
                                  unsigned short* W3p, unsigned short* Wqh,
                                  float* wv8, float* c0) {
  const int t = blockIdx.x * 256 + threadIdx.x;
  union { _Float16 h; unsigned short u; } cv;
  if (t < 65536) {
    const int ch = t >> 8, k = t & 255;
    // 32x32x16 k-major pack: dst = ks*4096 + ch*16 + h*8 + e
    const int dst = (k >> 4) * 4096 + ch * 16 + ((k >> 3) & 1) * 8 + (k & 7);
    cv.h = (_Float16)W1[(size_t)ch * 259 + k]; W1p[dst] = cv.u;
    cv.h = (_Float16)W2[t]; W2p[dst] = cv.u;
    cv.h = (_Float16)W3[t]; W3p[dst] = cv.u;
  }
  if (t < 16384) { cv.h = (_Float16)Wq[t]; Wqh[t] = cv.u; }  // row-major
  if (t < 256) {
    float s = 0.f;
    for (int o = 0; o < 256; ++o) s += Wv[(size_t)o * 256 + t] * W8[o];
    wv8[t] = s;
  }
  if (t == 0) {
    float s = 0.f;
    for (int o = 0; o < 256; ++o) s += bv[o] * W8[o];
    c0[0] = s + b8[0];
  }
}

// ---- transpose latents [B][256][N] -> fp16 [B][N][256] ----
extern "C" __global__ void transp(const float* __restrict__ latents,
                                  unsigned short* __restrict__ Lt, int N) {
  __shared__ unsigned short tile[256][68];
  const int b = blockIdx.y, n0 = blockIdx.x * 64, tid = threadIdx.x;
  const int nl = tid & 63;
  union { _Float16 h; unsigned short u; } cv;
  for (int c = tid >> 6; c < 256; c += 4) {
    const int n = n0 + nl;
    float v = (n < N) ? latents[((size_t)b * NLAT + c) * N + n] : 0.f;
    cv.h = (_Float16)v;
    tile[c][nl] = cv.u;
  }
  __syncthreads();
  const int nr = tid >> 2, cg = (tid & 3) * 64;
  const int n = n0 + nr;
  if (n < N) {
    for (int cc = 0; cc < 64; cc += 8) {
      f16x8 v;
#pragma unroll
      for (int j = 0; j < 8; ++j) {
        union { unsigned short u; _Float16 h; } bk;
        bk.u = tile[cg + cc + j][nr];
        v[j] = bk.h;
      }
      *(f16x8*)((_Float16*)Lt + ((size_t)b * N + n) * NLAT + cg + cc) = v;
    }
  }
}

extern "C" void kernel_launch(void* const* d_in, const int* in_sizes, int n_in,
                              void* d_out, int out_size, void* d_ws, size_t ws_size,
                              hipStream_t stream) {
  (void)n_in; (void)out_size;
  const float* latents = (const float*)d_in[0];
  const float* pts     = (const float*)d_in[1];
  const float* ptsq    = (const float*)d_in[2];
  const void*  proj    = d_in[3];
  const float* W1 = (const float*)d_in[4];  const float* b1 = (const float*)d_in[5];
  const float* W2 = (const float*)d_in[6];  const float* b2 = (const float*)d_in[7];
  const float* W3 = (const float*)d_in[8];  const float* b3 = (const float*)d_in[9];
  const float* Wq = (const float*)d_in[10]; const float* bq = (const float*)d_in[11];
  const float* Wv = (const float*)d_in[12]; const float* bv = (const float*)d_in[13];
  const float* W8 = (const float*)d_in[14]; const float* b8 = (const float*)d_in[15];
  float* out = (float*)d_out;

  const int B  = 2;
  const int N  = in_sizes[1] / (3 * B);
  const int NQ = in_sizes[2] / (3 * B);

  size_t off = 0;
  auto alloc = [&](size_t bytes) -> char* {
    char* p = (char*)d_ws + off;
    off += (bytes + 255) & ~(size_t)255;
    return p;
  };
  unsigned short* W1p = (unsigned short*)alloc(65536 * 2);
  unsigned short* W2p = (unsigned short*)alloc(65536 * 2);
  unsigned short* W3p = (unsigned short*)alloc(65536 * 2);
  unsigned short* Wqh = (unsigned short*)alloc(16384 * 2);
  float* wv8 = (float*)alloc(256 * 4);
  float* c0  = (float*)alloc(4);
  const size_t lt_bytes = (size_t)B * N * NLAT * 2;
  unsigned short* Lt = (unsigned short*)((char*)d_ws + off);
  const int use_lt = (off + lt_bytes <= ws_size) ? 1 : 0;

  hipLaunchKernelGGL(prep_w, dim3(256), dim3(256), 0, stream,
                     W1, W2, W3, Wq, Wv, W8, bv, b8, W1p, W2p, W3p, Wqh, wv8, c0);
  if (use_lt)
    hipLaunchKernelGGL(transp, dim3((N + 63) / 64, B), dim3(256), 0, stream,
                       latents, Lt, N);
  const int nblocks = (B * NQ + QB - 1) / QB;
  hipLaunchKernelGGL(interp_mfma, dim3(nblocks), dim3(256), 0, stream,
                     latents, pts, ptsq, proj, Lt, W1, W1p, W2p, W3p, Wqh,
                     b1, b2, b3, bq, wv8, c0, out, N, NQ, use_lt);
}